// Round 1
// baseline (65.294 us; speedup 1.0000x reference)
//
#include <hip/hip_runtime.h>
#include <hip/hip_bf16.h>

#define BLOCK 256
#define TILE 256   // matrices per LDS tile (== BLOCK, one matrix per thread)

// Stable first divided difference of log between x and y (both > 0):
// f[x,y] = (log y - log x)/(y - x), computed cancellation-free via log1p.
__device__ __forceinline__ float dd_log(float x, float y) {
    float d = y - x;
    float t = d / x;
    if (fabsf(t) > 1e-4f) return log1pf(t) / d;
    return (1.0f - 0.5f * t) / x;   // series: log1p(t)/t/x ≈ (1 - t/2)/x
}

// logm of a symmetric 3x3 SPD matrix, output as 6 unique entries
// L = {L00, L01, L02, L11, L12, L22}
__device__ __forceinline__ void logm3(float a00, float a01, float a02,
                                      float a11, float a12, float a22,
                                      float L[6]) {
    // --- eigenvalues via the trigonometric method (Smith) ---
    float q  = (a00 + a11 + a22) * (1.0f / 3.0f);
    float b00 = a00 - q, b11 = a11 - q, b22 = a22 - q;
    float p2 = b00*b00 + b11*b11 + b22*b22
             + 2.0f * (a01*a01 + a02*a02 + a12*a12);
    float p  = sqrtf(p2 * (1.0f / 6.0f));
    p = fmaxf(p, 1e-20f);                 // guard exact multiple of identity
    float ip = 1.0f / p;
    float c00 = b00*ip, c11 = b11*ip, c22 = b22*ip;
    float c01 = a01*ip, c02 = a02*ip, c12 = a12*ip;
    float detB = c00*(c11*c22 - c12*c12)
               - c01*(c01*c22 - c12*c02)
               + c02*(c01*c12 - c11*c02);
    float r = fminf(fmaxf(0.5f * detB, -1.0f), 1.0f);
    float phi = acosf(r) * (1.0f / 3.0f);
    float sph, cph;
    sincosf(phi, &sph, &cph);
    float whi = q + 2.0f * p * cph;                       // largest
    float wlo = q - p * (cph + 1.7320508075688772f * sph); // smallest
    float wmid = 3.0f * q - whi - wlo;                     // middle
    // SPD by construction (>= 0.5); clamp defensively for log
    float w0 = fmaxf(wlo,  1e-8f);
    float w1 = fmaxf(wmid, 1e-8f);
    float w2 = fmaxf(whi,  1e-8f);

    // --- Newton divided differences of log at (w0, w1, w2) ---
    float l0   = logf(w0);
    float dd01 = dd_log(w0, w1);
    float dd12 = dd_log(w1, w2);
    float span = w2 - w0;
    float dd012 = (span > 1e-5f * w1) ? (dd12 - dd01) / span
                                      : -0.5f / (w1 * w1);
    // p(x) = c0 + c1 x + c2 x^2 interpolating log at the eigenvalues
    float c2 = dd012;
    float c1 = dd01 - dd012 * (w0 + w1);
    float c0 = l0 - dd01 * w0 + dd012 * (w0 * w1);

    // --- A^2 (symmetric) ---
    float s00 = a00*a00 + a01*a01 + a02*a02;
    float s01 = a00*a01 + a01*a11 + a02*a12;
    float s02 = a00*a02 + a01*a12 + a02*a22;
    float s11 = a01*a01 + a11*a11 + a12*a12;
    float s12 = a01*a02 + a11*a12 + a12*a22;
    float s22 = a02*a02 + a12*a12 + a22*a22;

    L[0] = c0 + c1*a00 + c2*s00;
    L[1] =      c1*a01 + c2*s01;
    L[2] =      c1*a02 + c2*s02;
    L[3] = c0 + c1*a11 + c2*s11;
    L[4] =      c1*a12 + c2*s12;
    L[5] = c0 + c1*a22 + c2*s22;
}

__device__ __forceinline__ void load6(const float* a, float m[6]) {
    m[0] = a[0]; m[1] = a[1]; m[2] = a[2];
    m[3] = a[4]; m[4] = a[5]; m[5] = a[8];
}

__global__ void __launch_bounds__(BLOCK)
le_partial(const float* __restrict__ D1, const float* __restrict__ D2,
           float* __restrict__ partial, int n, int ntiles) {
    __shared__ float lds[TILE * 9];
    __shared__ float wsum[BLOCK / 64];
    float acc = 0.0f;

    for (int tile = blockIdx.x; tile < ntiles; tile += gridDim.x) {
        int base = tile * TILE;
        int cnt  = min(TILE, n - base);
        int nf   = cnt * 9;
        bool active = (int)threadIdx.x < cnt;

        __syncthreads();   // protect lds reuse from previous iteration
        {
            const float* src = D1 + (size_t)base * 9;
            for (int i = threadIdx.x; i < nf; i += BLOCK) lds[i] = src[i];
        }
        __syncthreads();

        float L1[6];
        if (active) {
            float m[6]; load6(&lds[threadIdx.x * 9], m);
            logm3(m[0], m[1], m[2], m[3], m[4], m[5], L1);
        }

        __syncthreads();
        {
            const float* src = D2 + (size_t)base * 9;
            for (int i = threadIdx.x; i < nf; i += BLOCK) lds[i] = src[i];
        }
        __syncthreads();

        if (active) {
            float m[6], L2[6]; load6(&lds[threadIdx.x * 9], m);
            logm3(m[0], m[1], m[2], m[3], m[4], m[5], L2);
            float d0 = L1[0] - L2[0], d1 = L1[1] - L2[1], d2 = L1[2] - L2[2];
            float d3 = L1[3] - L2[3], d4 = L1[4] - L2[4], d5 = L1[5] - L2[5];
            acc += d0*d0 + d3*d3 + d5*d5 + 2.0f * (d1*d1 + d2*d2 + d4*d4);
        }
    }

    // wave reduce (wave = 64)
    #pragma unroll
    for (int off = 32; off > 0; off >>= 1)
        acc += __shfl_down(acc, off, 64);
    if ((threadIdx.x & 63) == 0) wsum[threadIdx.x >> 6] = acc;
    __syncthreads();
    if (threadIdx.x == 0) {
        float s = 0.0f;
        #pragma unroll
        for (int i = 0; i < BLOCK / 64; ++i) s += wsum[i];
        partial[blockIdx.x] = s;
    }
}

__global__ void __launch_bounds__(BLOCK)
le_final(const float* __restrict__ partial, int nparts,
         float* __restrict__ out, double invN) {
    double s = 0.0;
    for (int i = threadIdx.x; i < nparts; i += BLOCK)
        s += (double)partial[i];
    #pragma unroll
    for (int off = 32; off > 0; off >>= 1)
        s += __shfl_down(s, off, 64);
    __shared__ double ws[BLOCK / 64];
    if ((threadIdx.x & 63) == 0) ws[threadIdx.x >> 6] = s;
    __syncthreads();
    if (threadIdx.x == 0) {
        double t = 0.0;
        #pragma unroll
        for (int i = 0; i < BLOCK / 64; ++i) t += ws[i];
        out[0] = (float)(t * invN);
    }
}

extern "C" void kernel_launch(void* const* d_in, const int* in_sizes, int n_in,
                              void* d_out, int out_size, void* d_ws, size_t ws_size,
                              hipStream_t stream) {
    const float* D1 = (const float*)d_in[0];
    const float* D2 = (const float*)d_in[1];
    float* out = (float*)d_out;
    float* partial = (float*)d_ws;

    int n = in_sizes[0] / 9;
    int ntiles = (n + TILE - 1) / TILE;

    int grid = ntiles < 2048 ? ntiles : 2048;
    int maxblocks = (int)(ws_size / sizeof(float));
    if (maxblocks > 0 && grid > maxblocks) grid = maxblocks;
    if (grid < 1) grid = 1;

    le_partial<<<grid, BLOCK, 0, stream>>>(D1, D2, partial, n, ntiles);
    le_final<<<1, BLOCK, 0, stream>>>(partial, grid, out, 1.0 / (double)n);
}

// Round 2
// 37.932 us; speedup vs baseline: 1.7213x; 1.7213x over previous
//
#include <hip/hip_runtime.h>
#include <hip/hip_bf16.h>

#define BLOCK 256
#define TILE 256   // matrices per LDS tile (== BLOCK, one matrix per thread)

__device__ __forceinline__ float frcp(float x) { return __builtin_amdgcn_rcpf(x); }
__device__ __forceinline__ float fsqrt(float x) { return __builtin_amdgcn_sqrtf(x); }

// fast acos: Abramowitz-Stegun 4.4.45, abs err ~6.7e-5 rad
__device__ __forceinline__ float facos(float x) {
    float ax = fabsf(x);
    float sq = fsqrt(fmaxf(1.0f - ax, 0.0f));
    float poly = fmaf(fmaf(fmaf(-0.0187293f, ax, 0.0742610f), ax, -0.2121144f),
                      ax, 1.5707288f);
    float ac = sq * poly;
    return (x < 0.0f) ? (3.14159274f - ac) : ac;
}

// logm of a symmetric 3x3 SPD matrix, output as 6 unique entries
// L = {L00, L01, L02, L11, L12, L22}
__device__ __forceinline__ void logm3(const float m[6], float L[6]) {
    float a00 = m[0], a01 = m[1], a02 = m[2];
    float a11 = m[3], a12 = m[4], a22 = m[5];

    // --- eigenvalues via the trigonometric method ---
    float q  = (a00 + a11 + a22) * (1.0f / 3.0f);
    float b00 = a00 - q, b11 = a11 - q, b22 = a22 - q;
    float p2 = b00*b00 + b11*b11 + b22*b22
             + 2.0f * (a01*a01 + a02*a02 + a12*a12);
    float p  = fsqrt(p2 * (1.0f / 6.0f));
    p = fmaxf(p, 1e-12f);                 // guard exact multiple of identity
    float ip = frcp(p);
    float c00 = b00*ip, c11 = b11*ip, c22 = b22*ip;
    float c01 = a01*ip, c02 = a02*ip, c12 = a12*ip;
    float detB = c00*(c11*c22 - c12*c12)
               - c01*(c01*c22 - c12*c02)
               + c02*(c01*c12 - c11*c02);
    float r = fminf(fmaxf(0.5f * detB, -1.0f), 1.0f);
    float phi = facos(r) * (1.0f / 3.0f);
    float sph = __sinf(phi), cph = __cosf(phi);   // native v_sin/v_cos, phi in [0,pi/3]
    float whi = q + 2.0f * p * cph;                        // largest
    float wlo = q - p * (cph + 1.7320508f * sph);          // smallest
    float wmid = 3.0f * q - whi - wlo;                     // middle
    float w0 = fmaxf(wlo,  1e-8f);
    float w1 = fmaxf(wmid, 1e-8f);
    float w2 = fmaxf(whi,  1e-8f);

    // --- Newton divided differences of log at (w0, w1, w2), native log/rcp ---
    float l0 = __logf(w0), l1 = __logf(w1), l2 = __logf(w2);
    float d01 = w1 - w0, d12 = w2 - w1, span = w2 - w0;
    float thr = 1e-3f * w1;
    float dd01 = (d01 > thr) ? (l1 - l0) * frcp(d01) : 2.0f * frcp(w0 + w1);
    float dd12 = (d12 > thr) ? (l2 - l1) * frcp(d12) : 2.0f * frcp(w1 + w2);
    float dd012 = (span > thr) ? (dd12 - dd01) * frcp(span)
                               : -0.5f * frcp(w1 * w1);
    // p(x) = c0 + c1 x + c2 x^2 interpolating log at the eigenvalues
    float k2 = dd012;
    float k1 = dd01 - dd012 * (w0 + w1);
    float k0 = l0 - dd01 * w0 + dd012 * (w0 * w1);

    // --- A^2 (symmetric) ---
    float s00 = a00*a00 + a01*a01 + a02*a02;
    float s01 = a00*a01 + a01*a11 + a02*a12;
    float s02 = a00*a02 + a01*a12 + a02*a22;
    float s11 = a01*a01 + a11*a11 + a12*a12;
    float s12 = a01*a02 + a11*a12 + a12*a22;
    float s22 = a02*a02 + a12*a12 + a22*a22;

    L[0] = k0 + k1*a00 + k2*s00;
    L[1] =      k1*a01 + k2*s01;
    L[2] =      k1*a02 + k2*s02;
    L[3] = k0 + k1*a11 + k2*s11;
    L[4] =      k1*a12 + k2*s12;
    L[5] = k0 + k1*a22 + k2*s22;
}

__device__ __forceinline__ void load6(const float* a, float m[6]) {
    m[0] = a[0]; m[1] = a[1]; m[2] = a[2];
    m[3] = a[4]; m[4] = a[5]; m[5] = a[8];
}

__device__ __forceinline__ void stage(const float* __restrict__ src, float* lds, int nf) {
    // src is 16B-aligned (tile base offset = tile*9216 bytes)
    int nv = nf >> 2;
    const float4* src4 = reinterpret_cast<const float4*>(src);
    float4* lds4 = reinterpret_cast<float4*>(lds);
    for (int i = threadIdx.x; i < nv; i += BLOCK) lds4[i] = src4[i];
    for (int i = (nv << 2) + threadIdx.x; i < nf; i += BLOCK) lds[i] = src[i];
}

__global__ void __launch_bounds__(BLOCK)
le_partial(const float* __restrict__ D1, const float* __restrict__ D2,
           float* __restrict__ partial, int n, int ntiles) {
    __shared__ float lds[TILE * 9];
    __shared__ float wsum[BLOCK / 64];
    float acc = 0.0f;

    for (int tile = blockIdx.x; tile < ntiles; tile += gridDim.x) {
        int base = tile * TILE;
        int cnt  = min(TILE, n - base);
        int nf   = cnt * 9;
        bool active = (int)threadIdx.x < cnt;

        __syncthreads();   // protect lds reuse from previous iteration
        stage(D1 + (size_t)base * 9, lds, nf);
        __syncthreads();

        float L1[6];
        if (active) {
            float m[6]; load6(&lds[threadIdx.x * 9], m);
            logm3(m, L1);
        }

        __syncthreads();
        stage(D2 + (size_t)base * 9, lds, nf);
        __syncthreads();

        if (active) {
            float m[6], L2[6]; load6(&lds[threadIdx.x * 9], m);
            logm3(m, L2);
            float d0 = L1[0] - L2[0], d1 = L1[1] - L2[1], d2 = L1[2] - L2[2];
            float d3 = L1[3] - L2[3], d4 = L1[4] - L2[4], d5 = L1[5] - L2[5];
            acc += d0*d0 + d3*d3 + d5*d5 + 2.0f * (d1*d1 + d2*d2 + d4*d4);
        }
    }

    // wave reduce (wave = 64)
    #pragma unroll
    for (int off = 32; off > 0; off >>= 1)
        acc += __shfl_down(acc, off, 64);
    if ((threadIdx.x & 63) == 0) wsum[threadIdx.x >> 6] = acc;
    __syncthreads();
    if (threadIdx.x == 0) {
        float s = 0.0f;
        #pragma unroll
        for (int i = 0; i < BLOCK / 64; ++i) s += wsum[i];
        partial[blockIdx.x] = s;
    }
}

__global__ void __launch_bounds__(BLOCK)
le_final(const float* __restrict__ partial, int nparts,
         float* __restrict__ out, double invN) {
    double s = 0.0;
    for (int i = threadIdx.x; i < nparts; i += BLOCK)
        s += (double)partial[i];
    #pragma unroll
    for (int off = 32; off > 0; off >>= 1)
        s += __shfl_down(s, off, 64);
    __shared__ double ws[BLOCK / 64];
    if ((threadIdx.x & 63) == 0) ws[threadIdx.x >> 6] = s;
    __syncthreads();
    if (threadIdx.x == 0) {
        double t = 0.0;
        #pragma unroll
        for (int i = 0; i < BLOCK / 64; ++i) t += ws[i];
        out[0] = (float)(t * invN);
    }
}

extern "C" void kernel_launch(void* const* d_in, const int* in_sizes, int n_in,
                              void* d_out, int out_size, void* d_ws, size_t ws_size,
                              hipStream_t stream) {
    const float* D1 = (const float*)d_in[0];
    const float* D2 = (const float*)d_in[1];
    float* out = (float*)d_out;
    float* partial = (float*)d_ws;

    int n = in_sizes[0] / 9;
    int ntiles = (n + TILE - 1) / TILE;

    int grid = ntiles < 2048 ? ntiles : 2048;
    int maxblocks = (int)(ws_size / sizeof(float));
    if (maxblocks > 0 && grid > maxblocks) grid = maxblocks;
    if (grid < 1) grid = 1;

    le_partial<<<grid, BLOCK, 0, stream>>>(D1, D2, partial, n, ntiles);
    le_final<<<1, BLOCK, 0, stream>>>(partial, grid, out, 1.0 / (double)n);
}

// Round 3
// 33.237 us; speedup vs baseline: 1.9645x; 1.1413x over previous
//
#include <hip/hip_runtime.h>
#include <hip/hip_bf16.h>

#define BLOCK 256
#define TILE 256   // matrices per tile; LDS holds D1-tile then D2-tile (18 KB)

__device__ __forceinline__ float frcp(float x) { return __builtin_amdgcn_rcpf(x); }
__device__ __forceinline__ float fsqrt(float x) { return __builtin_amdgcn_sqrtf(x); }

// fast acos: Abramowitz-Stegun 4.4.45, abs err ~6.7e-5 rad
__device__ __forceinline__ float facos(float x) {
    float ax = fabsf(x);
    float sq = fsqrt(fmaxf(1.0f - ax, 0.0f));
    float poly = fmaf(fmaf(fmaf(-0.0187293f, ax, 0.0742610f), ax, -0.2121144f),
                      ax, 1.5707288f);
    float ac = sq * poly;
    return (x < 0.0f) ? (3.14159274f - ac) : ac;
}

// logm of a symmetric 3x3 SPD matrix, output as 6 unique entries
// L = {L00, L01, L02, L11, L12, L22}
__device__ __forceinline__ void logm3(const float m[6], float L[6]) {
    float a00 = m[0], a01 = m[1], a02 = m[2];
    float a11 = m[3], a12 = m[4], a22 = m[5];

    float q  = (a00 + a11 + a22) * (1.0f / 3.0f);
    float b00 = a00 - q, b11 = a11 - q, b22 = a22 - q;
    float p2 = b00*b00 + b11*b11 + b22*b22
             + 2.0f * (a01*a01 + a02*a02 + a12*a12);
    float p  = fsqrt(p2 * (1.0f / 6.0f));
    p = fmaxf(p, 1e-12f);
    float ip = frcp(p);
    float c00 = b00*ip, c11 = b11*ip, c22 = b22*ip;
    float c01 = a01*ip, c02 = a02*ip, c12 = a12*ip;
    float detB = c00*(c11*c22 - c12*c12)
               - c01*(c01*c22 - c12*c02)
               + c02*(c01*c12 - c11*c02);
    float r = fminf(fmaxf(0.5f * detB, -1.0f), 1.0f);
    float phi = facos(r) * (1.0f / 3.0f);
    float sph = __sinf(phi), cph = __cosf(phi);
    float whi = q + 2.0f * p * cph;
    float wlo = q - p * (cph + 1.7320508f * sph);
    float wmid = 3.0f * q - whi - wlo;
    float w0 = fmaxf(wlo,  1e-8f);
    float w1 = fmaxf(wmid, 1e-8f);
    float w2 = fmaxf(whi,  1e-8f);

    float l0 = __logf(w0), l1 = __logf(w1), l2 = __logf(w2);
    float d01 = w1 - w0, d12 = w2 - w1, span = w2 - w0;
    float thr = 1e-3f * w1;
    float dd01 = (d01 > thr) ? (l1 - l0) * frcp(d01) : 2.0f * frcp(w0 + w1);
    float dd12 = (d12 > thr) ? (l2 - l1) * frcp(d12) : 2.0f * frcp(w1 + w2);
    float dd012 = (span > thr) ? (dd12 - dd01) * frcp(span)
                               : -0.5f * frcp(w1 * w1);
    float k2 = dd012;
    float k1 = dd01 - dd012 * (w0 + w1);
    float k0 = l0 - dd01 * w0 + dd012 * (w0 * w1);

    float s00 = a00*a00 + a01*a01 + a02*a02;
    float s01 = a00*a01 + a01*a11 + a02*a12;
    float s02 = a00*a02 + a01*a12 + a02*a22;
    float s11 = a01*a01 + a11*a11 + a12*a12;
    float s12 = a01*a02 + a11*a12 + a12*a22;
    float s22 = a02*a02 + a12*a12 + a22*a22;

    L[0] = k0 + k1*a00 + k2*s00;
    L[1] =      k1*a01 + k2*s01;
    L[2] =      k1*a02 + k2*s02;
    L[3] = k0 + k1*a11 + k2*s11;
    L[4] =      k1*a12 + k2*s12;
    L[5] = k0 + k1*a22 + k2*s22;
}

__device__ __forceinline__ void load6(const float* a, float m[6]) {
    m[0] = a[0]; m[1] = a[1]; m[2] = a[2];
    m[3] = a[4]; m[4] = a[5]; m[5] = a[8];
}

__device__ __forceinline__ float fnorm2_diff(const float L1[6], const float L2[6]) {
    float d0 = L1[0]-L2[0], d1 = L1[1]-L2[1], d2 = L1[2]-L2[2];
    float d3 = L1[3]-L2[3], d4 = L1[4]-L2[4], d5 = L1[5]-L2[5];
    return d0*d0 + d3*d3 + d5*d5 + 2.0f * (d1*d1 + d2*d2 + d4*d4);
}

// Issue the 9 coalesced float2 loads covering this tile's D1+D2 data.
// idx space: [0,1152) -> D1 floats [0,2304); [1152,2304) -> D2 floats [0,2304).
__device__ __forceinline__ void load_tile(float2 v[9],
                                          const float* __restrict__ D1,
                                          const float* __restrict__ D2,
                                          long tile, int tid) {
    const float2* s1 = reinterpret_cast<const float2*>(D1 + tile * (TILE * 9));
    const float2* s2 = reinterpret_cast<const float2*>(D2 + tile * (TILE * 9));
    #pragma unroll
    for (int k = 0; k < 9; ++k) {
        int idx = k * BLOCK + tid;
        v[k] = (idx < TILE * 9 / 2) ? s1[idx] : s2[idx - TILE * 9 / 2];
    }
}

__global__ void __launch_bounds__(BLOCK)
le_partial(const float* __restrict__ D1, const float* __restrict__ D2,
           float* __restrict__ partial, int n) {
    __shared__ float lds[TILE * 18];        // D1 tile at [0,2304), D2 tile at [2304,4608)
    __shared__ float wsum[BLOCK / 64];
    float2* lds2 = reinterpret_cast<float2*>(lds);
    const int tid = threadIdx.x;
    const int nfull = n / TILE;
    float acc = 0.0f;

    float2 v[9];
    long t = blockIdx.x;
    if (t < nfull) load_tile(v, D1, D2, t, tid);

    while (t < nfull) {
        __syncthreads();                    // previous tile's compute done: lds free
        #pragma unroll
        for (int k = 0; k < 9; ++k) lds2[k * BLOCK + tid] = v[k];
        long tn = t + gridDim.x;
        if (tn < nfull) load_tile(v, D1, D2, tn, tid);   // prefetch next tile
        __syncthreads();                    // lds ready

        float m1[6], m2[6], L1[6], L2[6];
        load6(&lds[tid * 9], m1);
        load6(&lds[TILE * 9 + tid * 9], m2);
        logm3(m1, L1);
        logm3(m2, L2);
        acc += fnorm2_diff(L1, L2);
        t = tn;
    }

    // tail (n % TILE matrices): direct global loads, no LDS, no barriers
    {
        int ti = nfull * TILE + blockIdx.x * BLOCK + tid;
        if (ti < n) {
            float m1[6], m2[6], L1[6], L2[6];
            load6(D1 + (size_t)ti * 9, m1);
            load6(D2 + (size_t)ti * 9, m2);
            logm3(m1, L1);
            logm3(m2, L2);
            acc += fnorm2_diff(L1, L2);
        }
    }

    // wave reduce (wave = 64)
    #pragma unroll
    for (int off = 32; off > 0; off >>= 1)
        acc += __shfl_down(acc, off, 64);
    if ((tid & 63) == 0) wsum[tid >> 6] = acc;
    __syncthreads();
    if (tid == 0) {
        float s = 0.0f;
        #pragma unroll
        for (int i = 0; i < BLOCK / 64; ++i) s += wsum[i];
        partial[blockIdx.x] = s;
    }
}

__global__ void __launch_bounds__(BLOCK)
le_final(const float* __restrict__ partial, int nparts,
         float* __restrict__ out, double invN) {
    double s = 0.0;
    for (int i = threadIdx.x; i < nparts; i += BLOCK)
        s += (double)partial[i];
    #pragma unroll
    for (int off = 32; off > 0; off >>= 1)
        s += __shfl_down(s, off, 64);
    __shared__ double ws[BLOCK / 64];
    if ((threadIdx.x & 63) == 0) ws[threadIdx.x >> 6] = s;
    __syncthreads();
    if (threadIdx.x == 0) {
        double t = 0.0;
        #pragma unroll
        for (int i = 0; i < BLOCK / 64; ++i) t += ws[i];
        out[0] = (float)(t * invN);
    }
}

extern "C" void kernel_launch(void* const* d_in, const int* in_sizes, int n_in,
                              void* d_out, int out_size, void* d_ws, size_t ws_size,
                              hipStream_t stream) {
    const float* D1 = (const float*)d_in[0];
    const float* D2 = (const float*)d_in[1];
    float* out = (float*)d_out;
    float* partial = (float*)d_ws;

    int n = in_sizes[0] / 9;
    int nfull = n / TILE;

    int grid = nfull < 2048 ? (nfull < 1 ? 1 : nfull) : 2048;
    int maxblocks = (int)(ws_size / sizeof(float));
    if (maxblocks > 0 && grid > maxblocks) grid = maxblocks;
    if (grid < 1) grid = 1;

    le_partial<<<grid, BLOCK, 0, stream>>>(D1, D2, partial, n);
    le_final<<<1, BLOCK, 0, stream>>>(partial, grid, out, 1.0 / (double)n);
}

// Round 4
// 33.006 us; speedup vs baseline: 1.9783x; 1.0070x over previous
//
#include <hip/hip_runtime.h>
#include <hip/hip_bf16.h>

#define BLOCK 256

__device__ __forceinline__ float frcp(float x) { return __builtin_amdgcn_rcpf(x); }
__device__ __forceinline__ float fsqrt(float x) { return __builtin_amdgcn_sqrtf(x); }

// fast acos: Abramowitz-Stegun 4.4.45, abs err ~6.7e-5 rad
__device__ __forceinline__ float facos(float x) {
    float ax = fabsf(x);
    float sq = fsqrt(fmaxf(1.0f - ax, 0.0f));
    float poly = fmaf(fmaf(fmaf(-0.0187293f, ax, 0.0742610f), ax, -0.2121144f),
                      ax, 1.5707288f);
    float ac = sq * poly;
    return (x < 0.0f) ? (3.14159274f - ac) : ac;
}

// logm of a symmetric 3x3 SPD matrix, output as 6 unique entries
// L = {L00, L01, L02, L11, L12, L22}
__device__ __forceinline__ void logm3(const float m[6], float L[6]) {
    float a00 = m[0], a01 = m[1], a02 = m[2];
    float a11 = m[3], a12 = m[4], a22 = m[5];

    float q  = (a00 + a11 + a22) * (1.0f / 3.0f);
    float b00 = a00 - q, b11 = a11 - q, b22 = a22 - q;
    float p2 = b00*b00 + b11*b11 + b22*b22
             + 2.0f * (a01*a01 + a02*a02 + a12*a12);
    float p  = fsqrt(p2 * (1.0f / 6.0f));
    p = fmaxf(p, 1e-12f);
    float ip = frcp(p);
    // det(B) on unnormalized B, then scale by ip^3 (saves 6 normalizing muls)
    float detB = b00*(b11*b22 - a12*a12)
               - a01*(a01*b22 - a12*a02)
               + a02*(a01*a12 - b11*a02);
    float ip3 = ip * ip * ip;
    float r = fminf(fmaxf(0.5f * detB * ip3, -1.0f), 1.0f);
    float phi = facos(r) * (1.0f / 3.0f);
    float sph = __sinf(phi), cph = __cosf(phi);
    float whi = q + 2.0f * p * cph;
    float wlo = q - p * (cph + 1.7320508f * sph);
    float wmid = 3.0f * q - whi - wlo;
    float w0 = fmaxf(wlo,  1e-8f);
    float w1 = fmaxf(wmid, 1e-8f);
    float w2 = fmaxf(whi,  1e-8f);

    float l0 = __logf(w0), l1 = __logf(w1), l2 = __logf(w2);
    float d01 = w1 - w0, d12 = w2 - w1, span = w2 - w0;
    float thr = 1e-3f * w1;
    float dd01 = (d01 > thr) ? (l1 - l0) * frcp(d01) : 2.0f * frcp(w0 + w1);
    float dd12 = (d12 > thr) ? (l2 - l1) * frcp(d12) : 2.0f * frcp(w1 + w2);
    float dd012 = (span > thr) ? (dd12 - dd01) * frcp(span)
                               : -0.5f * frcp(w1 * w1);
    float k2 = dd012;
    float k1 = dd01 - dd012 * (w0 + w1);
    float k0 = l0 - dd01 * w0 + dd012 * (w0 * w1);

    float s00 = a00*a00 + a01*a01 + a02*a02;
    float s01 = a00*a01 + a01*a11 + a02*a12;
    float s02 = a00*a02 + a01*a12 + a02*a22;
    float s11 = a01*a01 + a11*a11 + a12*a12;
    float s12 = a01*a02 + a11*a12 + a12*a22;
    float s22 = a02*a02 + a12*a12 + a22*a22;

    L[0] = k0 + k1*a00 + k2*s00;
    L[1] =      k1*a01 + k2*s01;
    L[2] =      k1*a02 + k2*s02;
    L[3] = k0 + k1*a11 + k2*s11;
    L[4] =      k1*a12 + k2*s12;
    L[5] = k0 + k1*a22 + k2*s22;
}

__device__ __forceinline__ void load6(const float* __restrict__ a, float m[6]) {
    m[0] = a[0]; m[1] = a[1]; m[2] = a[2];
    m[3] = a[4]; m[4] = a[5]; m[5] = a[8];
}

__device__ __forceinline__ float fnorm2_diff(const float L1[6], const float L2[6]) {
    float d0 = L1[0]-L2[0], d1 = L1[1]-L2[1], d2 = L1[2]-L2[2];
    float d3 = L1[3]-L2[3], d4 = L1[4]-L2[4], d5 = L1[5]-L2[5];
    return d0*d0 + d3*d3 + d5*d5 + 2.0f * (d1*d1 + d2*d2 + d4*d4);
}

__global__ void __launch_bounds__(BLOCK)
le_partial(const float* __restrict__ D1, const float* __restrict__ D2,
           float* __restrict__ partial, int n) {
    const int tid = threadIdx.x;
    const long stride = (long)gridDim.x * BLOCK;
    long i = (long)blockIdx.x * BLOCK + tid;
    float acc = 0.0f;

    float m1[6], m2[6];
    bool have = (i < n);
    if (have) { load6(D1 + i * 9, m1); load6(D2 + i * 9, m2); }

    while (have) {
        // prefetch next iteration's matrices while this one's compute runs
        long inext = i + stride;
        bool hn = (inext < n);
        float n1[6], n2[6];
        if (hn) { load6(D1 + inext * 9, n1); load6(D2 + inext * 9, n2); }

        float L1[6], L2[6];
        logm3(m1, L1);
        logm3(m2, L2);
        acc += fnorm2_diff(L1, L2);

        #pragma unroll
        for (int k = 0; k < 6; ++k) { m1[k] = n1[k]; m2[k] = n2[k]; }
        i = inext;
        have = hn;
    }

    // wave reduce (wave = 64)
    #pragma unroll
    for (int off = 32; off > 0; off >>= 1)
        acc += __shfl_down(acc, off, 64);
    __shared__ float wsum[BLOCK / 64];
    if ((tid & 63) == 0) wsum[tid >> 6] = acc;
    __syncthreads();
    if (tid == 0) {
        float s = 0.0f;
        #pragma unroll
        for (int i2 = 0; i2 < BLOCK / 64; ++i2) s += wsum[i2];
        partial[blockIdx.x] = s;
    }
}

__global__ void __launch_bounds__(BLOCK)
le_final(const float* __restrict__ partial, int nparts,
         float* __restrict__ out, double invN) {
    double s = 0.0;
    for (int i = threadIdx.x; i < nparts; i += BLOCK)
        s += (double)partial[i];
    #pragma unroll
    for (int off = 32; off > 0; off >>= 1)
        s += __shfl_down(s, off, 64);
    __shared__ double ws[BLOCK / 64];
    if ((threadIdx.x & 63) == 0) ws[threadIdx.x >> 6] = s;
    __syncthreads();
    if (threadIdx.x == 0) {
        double t = 0.0;
        #pragma unroll
        for (int i = 0; i < BLOCK / 64; ++i) t += ws[i];
        out[0] = (float)(t * invN);
    }
}

extern "C" void kernel_launch(void* const* d_in, const int* in_sizes, int n_in,
                              void* d_out, int out_size, void* d_ws, size_t ws_size,
                              hipStream_t stream) {
    const float* D1 = (const float*)d_in[0];
    const float* D2 = (const float*)d_in[1];
    float* out = (float*)d_out;
    float* partial = (float*)d_ws;

    int n = in_sizes[0] / 9;
    int nblk = (n + BLOCK - 1) / BLOCK;

    int grid = nblk < 2048 ? nblk : 2048;
    int maxblocks = (int)(ws_size / sizeof(float));
    if (maxblocks > 0 && grid > maxblocks) grid = maxblocks;
    if (grid < 1) grid = 1;

    le_partial<<<grid, BLOCK, 0, stream>>>(D1, D2, partial, n);
    le_final<<<1, BLOCK, 0, stream>>>(partial, grid, out, 1.0 / (double)n);
}